// Round 3
// baseline (2108.077 us; speedup 1.0000x reference)
//
#include <hip/hip_runtime.h>
#include <hip/hip_bf16.h>

#define N_USERS    50000
#define N_ENTITIES 100000
#define EMB        64
#define N_EDGES    2000000
#define NNZ        2000000
#define SLOPE      0.2f

#define RROWS   128                 // rows per bucket (LDS acc = 128*64*4 = 32 KB)
#define RSHIFT  7
#define NBK     782                 // ceil(100000/128)
#define NBU     391                 // ceil(50000/128)
#define CHUNK   8192                // edges per partition block
#define PB      ((N_EDGES + CHUNK - 1) / CHUNK)   // 245

// ============================================================================
// Pass 0: fused bucket histograms (LDS-privatized)
// ============================================================================
__global__ __launch_bounds__(256) void hist_both(const int* __restrict__ head,
                                                 const int* __restrict__ urows,
                                                 int* __restrict__ kgOffs,
                                                 int* __restrict__ uOffs) {
    __shared__ int lhk[NBK];
    __shared__ int lhu[NBU];
    int tid = threadIdx.x;
    for (int t = tid; t < NBK; t += 256) lhk[t] = 0;
    for (int t = tid; t < NBU; t += 256) lhu[t] = 0;
    __syncthreads();
    int base = blockIdx.x * CHUNK;
#pragma unroll 4
    for (int j = 0; j < CHUNK / 256; ++j) {
        int i = base + j * 256 + tid;
        if (i < N_EDGES) atomicAdd(&lhk[head[i] >> RSHIFT], 1);
        if (i < NNZ)     atomicAdd(&lhu[urows[i] >> RSHIFT], 1);
    }
    __syncthreads();
    for (int t = tid; t < NBK; t += 256) { int c = lhk[t]; if (c) atomicAdd(&kgOffs[t], c); }
    for (int t = tid; t < NBU; t += 256) { int c = lhu[t]; if (c) atomicAdd(&uOffs[t], c); }
}

// ============================================================================
// Pass 1: exclusive scan of both bucket histograms (grid = 2 blocks)
// ============================================================================
__global__ void scan_both(int* __restrict__ kgOffs, int* __restrict__ kgCur,
                          int* __restrict__ uOffs, int* __restrict__ uCur) {
    __shared__ int tmp[1024];
    int n    = (blockIdx.x == 0) ? NBK : NBU;
    int* offs = (blockIdx.x == 0) ? kgOffs : uOffs;
    int* cur  = (blockIdx.x == 0) ? kgCur : uCur;
    int tid = threadIdx.x;
    int v = (tid < n) ? offs[tid] : 0;
    tmp[tid] = v;
    __syncthreads();
    for (int off = 1; off < 1024; off <<= 1) {
        int t = (tid >= off) ? tmp[tid - off] : 0;
        __syncthreads();
        tmp[tid] += t;
        __syncthreads();
    }
    if (tid < n) { int e = tmp[tid] - v; offs[tid] = e; cur[tid] = e; }
    if (tid == n - 1) offs[n] = tmp[tid];
}

// ============================================================================
// Pass 2: bucket partition with block-local reservation (coalesced-run writes)
// kg payload: tail(0..16) | type-1 (17..20) | rowlow (21..27)
// ============================================================================
__global__ __launch_bounds__(256) void scatter_kg(const int* __restrict__ head,
                                                  const int* __restrict__ tail,
                                                  const int* __restrict__ etype,
                                                  int* __restrict__ cur,
                                                  int* __restrict__ pay) {
    __shared__ int lh[NBK];
    __shared__ int lb[NBK];
    int tid = threadIdx.x;
    int base = blockIdx.x * CHUNK;
    for (int t = tid; t < NBK; t += 256) lh[t] = 0;
    __syncthreads();
#pragma unroll 4
    for (int j = 0; j < CHUNK / 256; ++j) {
        int i = base + j * 256 + tid;
        if (i < N_EDGES) atomicAdd(&lh[head[i] >> RSHIFT], 1);
    }
    __syncthreads();
    for (int t = tid; t < NBK; t += 256) {
        int c = lh[t];
        lb[t] = c ? atomicAdd(&cur[t], c) : 0;
        lh[t] = 0;
    }
    __syncthreads();
#pragma unroll 4
    for (int j = 0; j < CHUNK / 256; ++j) {
        int i = base + j * 256 + tid;
        if (i < N_EDGES) {
            int h = head[i];
            int b = h >> RSHIFT;
            int p = lb[b] + atomicAdd(&lh[b], 1);
            pay[p] = tail[i] | ((etype[i] - 1) << 17) | ((h & (RROWS - 1)) << 21);
        }
    }
}

// user payload: int2 { col(0..16)|rowlow(17..23), val_bits }
__global__ __launch_bounds__(256) void scatter_user(const int* __restrict__ urows,
                                                    const int* __restrict__ ucols,
                                                    const float* __restrict__ uvals,
                                                    int* __restrict__ cur,
                                                    int2* __restrict__ pay) {
    __shared__ int lh[NBU];
    __shared__ int lb[NBU];
    int tid = threadIdx.x;
    int base = blockIdx.x * CHUNK;
    for (int t = tid; t < NBU; t += 256) lh[t] = 0;
    __syncthreads();
#pragma unroll 4
    for (int j = 0; j < CHUNK / 256; ++j) {
        int i = base + j * 256 + tid;
        if (i < NNZ) atomicAdd(&lh[urows[i] >> RSHIFT], 1);
    }
    __syncthreads();
    for (int t = tid; t < NBU; t += 256) {
        int c = lh[t];
        lb[t] = c ? atomicAdd(&cur[t], c) : 0;
        lh[t] = 0;
    }
    __syncthreads();
#pragma unroll 4
    for (int j = 0; j < CHUNK / 256; ++j) {
        int i = base + j * 256 + tid;
        if (i < NNZ) {
            int r = urows[i];
            int b = r >> RSHIFT;
            int p = lb[b] + atomicAdd(&lh[b], 1);
            pay[p] = make_int2(ucols[i] | ((r & (RROWS - 1)) << 17),
                               __float_as_int(uvals[i]));
        }
    }
}

// ============================================================================
// Pass 3a: KG accumulate — one block per bucket, LDS f32 accumulators,
// mean-divide fused into epilogue.
// ============================================================================
__global__ __launch_bounds__(256) void acc_kg(const int* __restrict__ pay,
                                              const int* __restrict__ offs,
                                              const float* __restrict__ entity_emb,
                                              const float* __restrict__ weight,
                                              float* __restrict__ out) {
    __shared__ float acc[RROWS * EMB];
    __shared__ int cnt[RROWS];
    int tid = threadIdx.x, d = tid & 63, wv = tid >> 6;
    for (int t = tid; t < RROWS * EMB; t += 256) acc[t] = 0.f;
    for (int t = tid; t < RROWS; t += 256) cnt[t] = 0;
    __syncthreads();
    int start = offs[blockIdx.x], end = offs[blockIdx.x + 1];
    int i = start + wv;
    for (; i + 4 < end; i += 8) {
        int v0 = pay[i], v1 = pay[i + 4];
        float a0 = entity_emb[(v0 & 0x1FFFF) * EMB + d] * weight[((v0 >> 17) & 15) * EMB + d];
        float a1 = entity_emb[(v1 & 0x1FFFF) * EMB + d] * weight[((v1 >> 17) & 15) * EMB + d];
        int r0 = (v0 >> 21) & (RROWS - 1), r1 = (v1 >> 21) & (RROWS - 1);
        atomicAdd(&acc[r0 * EMB + d], a0);
        atomicAdd(&acc[r1 * EMB + d], a1);
        if (d == 0) { atomicAdd(&cnt[r0], 1); atomicAdd(&cnt[r1], 1); }
    }
    if (i < end) {
        int v = pay[i];
        float a = entity_emb[(v & 0x1FFFF) * EMB + d] * weight[((v >> 17) & 15) * EMB + d];
        int r = (v >> 21) & (RROWS - 1);
        atomicAdd(&acc[r * EMB + d], a);
        if (d == 0) atomicAdd(&cnt[r], 1);
    }
    __syncthreads();
    int rowbase = blockIdx.x * RROWS;
    for (int r = wv; r < RROWS; r += 4) {
        int gr = rowbase + r;
        if (gr < N_ENTITIES)
            out[gr * EMB + d] = acc[r * EMB + d] / fmaxf((float)cnt[r], 1.f);
    }
}

// ============================================================================
// Pass 3b: user accumulate + fused attention gating epilogue.
// ============================================================================
__global__ __launch_bounds__(256) void acc_user(const int2* __restrict__ pay,
                                                const int* __restrict__ offs,
                                                const float* __restrict__ entity_emb,
                                                const float* __restrict__ user_emb,
                                                const float* __restrict__ P,
                                                const float* __restrict__ cvec,
                                                const float* __restrict__ W_user_att,
                                                const float* __restrict__ b_user_att,
                                                const float* __restrict__ latent_new,
                                                float* __restrict__ out) {
    __shared__ float acc[RROWS * EMB];
    int tid = threadIdx.x, d = tid & 63, wv = tid >> 6;
    for (int t = tid; t < RROWS * EMB; t += 256) acc[t] = 0.f;
    __syncthreads();
    int start = offs[blockIdx.x], end = offs[blockIdx.x + 1];
    int i = start + wv;
    for (; i + 4 < end; i += 8) {
        int2 v0 = pay[i], v1 = pay[i + 4];
        float a0 = __int_as_float(v0.y) * entity_emb[(v0.x & 0x1FFFF) * EMB + d];
        float a1 = __int_as_float(v1.y) * entity_emb[(v1.x & 0x1FFFF) * EMB + d];
        atomicAdd(&acc[((v0.x >> 17) & (RROWS - 1)) * EMB + d], a0);
        atomicAdd(&acc[((v1.x >> 17) & (RROWS - 1)) * EMB + d], a1);
    }
    if (i < end) {
        int2 v = pay[i];
        float a = __int_as_float(v.y) * entity_emb[(v.x & 0x1FFFF) * EMB + d];
        atomicAdd(&acc[((v.x >> 17) & (RROWS - 1)) * EMB + d], a);
    }
    __syncthreads();

    int rowbase = blockIdx.x * RROWS;
    for (int r = wv; r < RROWS; r += 4) {
        int gr = rowbase + r;
        if (gr >= N_USERS) continue;   // wave-uniform
        float ue = user_emb[gr * EMB + d];
        float s[8];
#pragma unroll
        for (int f = 0; f < 8; ++f) s[f] = ue * P[d * 8 + f];
#pragma unroll
        for (int off = 32; off; off >>= 1) {
#pragma unroll
            for (int f = 0; f < 8; ++f) s[f] += __shfl_xor(s[f], off, 64);
        }
#pragma unroll
        for (int f = 0; f < 8; ++f) s[f] += cvec[f];

        float att[8];
        float mx = -1e30f;
#pragma unroll
        for (int k = 0; k < 8; ++k) {
            float a = b_user_att[k];
#pragma unroll
            for (int j = 0; j < 8; ++j) a += s[j] * W_user_att[k * 8 + j];
            a = a > 0.f ? a : SLOPE * a;
            att[k] = a;
            mx = fmaxf(mx, a);
        }
        float sum = 0.f;
#pragma unroll
        for (int k = 0; k < 8; ++k) { att[k] = __expf(att[k] - mx); sum += att[k]; }
        float inv = 1.f / sum;
        float g = 0.f;
#pragma unroll
        for (int f = 0; f < 8; ++f) g += att[f] * inv * latent_new[f * EMB + d];
        out[gr * EMB + d] = acc[r * EMB + d] * (1.f + g);
    }
}

// ============================================================================
// Small dense math (one wave): latent_new, P = W1^T·lat1^T, c = b1·lat1^T
// ============================================================================
__global__ void small_dense(const float* __restrict__ latent_emb,
                            const float* __restrict__ weight,
                            const float* __restrict__ W_weight_att,
                            const float* __restrict__ b_weight_att,
                            const float* __restrict__ W1,
                            const float* __restrict__ b1,
                            const float* __restrict__ W2,
                            const float* __restrict__ b2,
                            float* __restrict__ P_out,
                            float* __restrict__ c_out,
                            float* __restrict__ latent_new_out) {
    __shared__ float lat1[8 * 64];
    __shared__ float lat2[8 * 64];
    __shared__ float wl2[16 * 64];
    __shared__ float srp[8 * 16];
    __shared__ float soft[8 * 16];
    int l = threadIdx.x;  // 0..63

    for (int f = 0; f < 8; ++f) {
        float a1 = b1[l], a2 = b2[l];
        for (int k = 0; k < 64; ++k) {
            float le = latent_emb[f * 64 + k];
            a1 += le * W1[l * 64 + k];
            a2 += le * W2[l * 64 + k];
        }
        lat1[f * 64 + l] = a1;
        lat2[f * 64 + l] = a2;
    }
    for (int r = 0; r < 16; ++r) {
        float a = b2[l];
        for (int k = 0; k < 64; ++k) a += weight[r * 64 + k] * W2[l * 64 + k];
        wl2[r * 64 + l] = a;
    }
    __syncthreads();

    for (int f = 0; f < 8; ++f) {
        float p = 0.f;
        for (int d = 0; d < 64; ++d) p += W1[d * 64 + l] * lat1[f * 64 + d];
        P_out[l * 8 + f] = p;
    }
    if (l < 8) {
        float cc = 0.f;
        for (int d = 0; d < 64; ++d) cc += b1[d] * lat1[l * 64 + d];
        c_out[l] = cc;
    }
    for (int idx = l; idx < 128; idx += 64) {
        int f = idx >> 4, r = idx & 15;
        float a = 0.f;
        for (int d = 0; d < 64; ++d) a += lat2[f * 64 + d] * wl2[r * 64 + d];
        srp[idx] = a;
    }
    __syncthreads();

    if (l < 8) {
        int f = l;
        float att[16];
        float mx = -1e30f;
        for (int k = 0; k < 16; ++k) {
            float a = b_weight_att[k];
            for (int j = 0; j < 16; ++j) a += srp[f * 16 + j] * W_weight_att[k * 16 + j];
            a = a > 0.f ? a : SLOPE * a;
            att[k] = a;
            mx = fmaxf(mx, a);
        }
        float s = 0.f;
        for (int k = 0; k < 16; ++k) { att[k] = expf(att[k] - mx); s += att[k]; }
        float inv = 1.f / s;
        for (int k = 0; k < 16; ++k) soft[f * 16 + k] = att[k] * inv;
    }
    __syncthreads();

    for (int f = 0; f < 8; ++f) {
        float a = 0.f;
        for (int r = 0; r < 16; ++r) a += soft[f * 16 + r] * weight[r * 64 + l];
        latent_new_out[f * 64 + l] = a;
    }
}

// ============================================================================
// Fallback atomic path (verified) — only if ws too small
// ============================================================================
__global__ void kg_scatter(const int* __restrict__ head, const int* __restrict__ tail,
                           const int* __restrict__ etype,
                           const float* __restrict__ entity_emb,
                           const float* __restrict__ weight,
                           float* __restrict__ sums, float* __restrict__ cnt) {
    int gid = blockIdx.x * blockDim.x + threadIdx.x;
    int e = gid >> 6, d = threadIdx.x & 63;
    if (e >= N_EDGES) return;
    int h = head[e], t = tail[e], w = etype[e] - 1;
    float v = entity_emb[t * EMB + d] * weight[w * EMB + d];
    unsafeAtomicAdd(&sums[h * EMB + d], v);
    if (d == 0) unsafeAtomicAdd(&cnt[h], 1.0f);
}

__global__ void user_scatter(const int* __restrict__ rows, const int* __restrict__ cols,
                             const float* __restrict__ vals,
                             const float* __restrict__ entity_emb,
                             float* __restrict__ user_sums) {
    int gid = blockIdx.x * blockDim.x + threadIdx.x;
    int e = gid >> 6, d = threadIdx.x & 63;
    if (e >= NNZ) return;
    float v = vals[e] * entity_emb[cols[e] * EMB + d];
    unsafeAtomicAdd(&user_sums[rows[e] * EMB + d], v);
}

__global__ void entity_div(float* __restrict__ ent, const float* __restrict__ cnt) {
    int gid = blockIdx.x * blockDim.x + threadIdx.x;
    if (gid >= N_ENTITIES * EMB) return;
    float c = cnt[gid >> 6];
    ent[gid] = ent[gid] / fmaxf(c, 1.0f);
}

__global__ void user_finalize(const float* __restrict__ user_emb,
                              const float* __restrict__ P,
                              const float* __restrict__ c,
                              const float* __restrict__ W_user_att,
                              const float* __restrict__ b_user_att,
                              const float* __restrict__ latent_new,
                              float* __restrict__ user_out) {
    int gid = blockIdx.x * blockDim.x + threadIdx.x;
    int u = gid >> 6, lane = threadIdx.x & 63;
    if (u >= N_USERS) return;
    float ue = user_emb[u * 64 + lane];
    float s[8];
#pragma unroll
    for (int f = 0; f < 8; ++f) s[f] = ue * P[lane * 8 + f];
#pragma unroll
    for (int off = 32; off; off >>= 1)
#pragma unroll
        for (int f = 0; f < 8; ++f) s[f] += __shfl_xor(s[f], off, 64);
#pragma unroll
    for (int f = 0; f < 8; ++f) s[f] += c[f];
    float att[8], mx = -1e30f;
#pragma unroll
    for (int k = 0; k < 8; ++k) {
        float a = b_user_att[k];
#pragma unroll
        for (int j = 0; j < 8; ++j) a += s[j] * W_user_att[k * 8 + j];
        a = a > 0.f ? a : SLOPE * a;
        att[k] = a;
        mx = fmaxf(mx, a);
    }
    float sum = 0.f;
#pragma unroll
    for (int k = 0; k < 8; ++k) { att[k] = expf(att[k] - mx); sum += att[k]; }
    float inv = 1.f / sum, g = 0.f;
#pragma unroll
    for (int f = 0; f < 8; ++f) g += att[f] * inv * latent_new[f * 64 + lane];
    float ua = user_out[u * 64 + lane];
    user_out[u * 64 + lane] = ua * (1.f + g);
}

extern "C" void kernel_launch(void* const* d_in, const int* in_sizes, int n_in,
                              void* d_out, int out_size, void* d_ws, size_t ws_size,
                              hipStream_t stream) {
    const float* entity_emb   = (const float*)d_in[0];
    const float* user_emb     = (const float*)d_in[1];
    const float* latent_emb   = (const float*)d_in[2];
    const int*   edge_index   = (const int*)d_in[3];
    const int*   edge_type    = (const int*)d_in[4];
    const int*   irows        = (const int*)d_in[5];
    const int*   icols        = (const int*)d_in[6];
    const float* ivals        = (const float*)d_in[7];
    const float* weight       = (const float*)d_in[8];
    const float* W_user_att   = (const float*)d_in[10];
    const float* b_user_att   = (const float*)d_in[11];
    const float* W_weight_att = (const float*)d_in[12];
    const float* b_weight_att = (const float*)d_in[13];
    const float* W1           = (const float*)d_in[14];
    const float* b1           = (const float*)d_in[15];
    const float* W2           = (const float*)d_in[16];
    const float* b2           = (const float*)d_in[17];

    float* out      = (float*)d_out;
    float* ent_out  = out;
    float* user_out = out + (size_t)N_ENTITIES * EMB;
    float* lat_out  = user_out + (size_t)N_USERS * EMB;

    const int* head = edge_index;
    const int* tail = edge_index + N_EDGES;

    // ---- workspace layout ----
    int* ws_i = (int*)d_ws;
    int*   kgOffs = ws_i;                       // NBK+1 = 783
    int*   uOffs  = kgOffs + (NBK + 1);         // NBU+1 = 392
    int*   kgCur  = uOffs + (NBU + 1);          // 782
    int*   uCur   = kgCur + NBK;                // 391
    int*   kgPay  = uCur + NBU;                 // 2,000,000
    int2*  uPay   = (int2*)(kgPay + N_EDGES);   // 2,000,000 int2 (8B-aligned: even int idx)
    float* Pbuf   = (float*)(uPay + NNZ);       // 512
    float* cbuf   = Pbuf + 64 * 8;              // 8
    size_t need_bytes = (size_t)((NBK + 1) + (NBU + 1) + NBK + NBU +
                                 N_EDGES + 2 * (size_t)NNZ + 512 + 8) * 4;

    if (ws_size >= need_bytes) {
        // zero both histogram regions in one memset (they are contiguous)
        hipMemsetAsync(kgOffs, 0, (size_t)((NBK + 1) + (NBU + 1)) * sizeof(int), stream);

        hist_both<<<PB, 256, 0, stream>>>(head, irows, kgOffs, uOffs);
        scan_both<<<2, 1024, 0, stream>>>(kgOffs, kgCur, uOffs, uCur);
        scatter_kg<<<PB, 256, 0, stream>>>(head, tail, edge_type, kgCur, kgPay);
        scatter_user<<<PB, 256, 0, stream>>>(irows, icols, ivals, uCur, uPay);
        small_dense<<<1, 64, 0, stream>>>(latent_emb, weight, W_weight_att,
                                          b_weight_att, W1, b1, W2, b2,
                                          Pbuf, cbuf, lat_out);
        acc_kg<<<NBK, 256, 0, stream>>>(kgPay, kgOffs, entity_emb, weight, ent_out);
        acc_user<<<NBU, 256, 0, stream>>>(uPay, uOffs, entity_emb, user_emb,
                                          Pbuf, cbuf, W_user_att, b_user_att,
                                          lat_out, user_out);
    } else {
        // ---------- fallback atomic path ----------
        float* cnt   = (float*)d_ws;
        float* Pbuf2 = cnt + N_ENTITIES;
        float* cbuf2 = Pbuf2 + 64 * 8;
        hipMemsetAsync(ent_out, 0,
                       (size_t)(N_ENTITIES + N_USERS) * EMB * sizeof(float), stream);
        hipMemsetAsync(cnt, 0, N_ENTITIES * sizeof(float), stream);
        int blocks_edges = (N_EDGES * 64) / 256;
        kg_scatter<<<blocks_edges, 256, 0, stream>>>(head, tail, edge_type, entity_emb,
                                                     weight, ent_out, cnt);
        user_scatter<<<blocks_edges, 256, 0, stream>>>(irows, icols, ivals, entity_emb,
                                                       user_out);
        small_dense<<<1, 64, 0, stream>>>(latent_emb, weight, W_weight_att,
                                          b_weight_att, W1, b1, W2, b2,
                                          Pbuf2, cbuf2, lat_out);
        user_finalize<<<(N_USERS * 64) / 256, 256, 0, stream>>>(user_emb, Pbuf2, cbuf2,
                                                                W_user_att, b_user_att,
                                                                lat_out, user_out);
        entity_div<<<(N_ENTITIES * EMB) / 256, 256, 0, stream>>>(ent_out, cnt);
    }
}

// Round 4
// 1830.154 us; speedup vs baseline: 1.1519x; 1.1519x over previous
//
#include <hip/hip_runtime.h>
#include <hip/hip_bf16.h>

#define N_USERS    50000
#define N_ENTITIES 100000
#define EMB        64
#define N_EDGES    2000000
#define NNZ        2000000
#define SLOPE      0.2f

#define BROWS   32                  // rows per bucket (LDS acc = 32*64*4 = 8 KB)
#define BSHIFT  5
#define NBK     ((N_ENTITIES + BROWS - 1) / BROWS)   // 3125
#define NBU     ((N_USERS + BROWS - 1) / BROWS)      // 1563
#define CHUNK   4096                // edges per partition block
#define PB      ((N_EDGES + CHUNK - 1) / CHUNK)      // 489

// ============================================================================
// Pass 0: fused bucket histograms (LDS-privatized)
// ============================================================================
__global__ __launch_bounds__(256) void hist_both(const int* __restrict__ head,
                                                 const int* __restrict__ urows,
                                                 int* __restrict__ kgOffs,
                                                 int* __restrict__ uOffs) {
    __shared__ int lhk[NBK];
    __shared__ int lhu[NBU];
    int tid = threadIdx.x;
    for (int t = tid; t < NBK; t += 256) lhk[t] = 0;
    for (int t = tid; t < NBU; t += 256) lhu[t] = 0;
    __syncthreads();
    int base = blockIdx.x * CHUNK;
#pragma unroll 4
    for (int j = 0; j < CHUNK / 256; ++j) {
        int i = base + j * 256 + tid;
        if (i < N_EDGES) atomicAdd(&lhk[head[i] >> BSHIFT], 1);
        if (i < NNZ)     atomicAdd(&lhu[urows[i] >> BSHIFT], 1);
    }
    __syncthreads();
    for (int t = tid; t < NBK; t += 256) { int c = lhk[t]; if (c) atomicAdd(&kgOffs[t], c); }
    for (int t = tid; t < NBU; t += 256) { int c = lhu[t]; if (c) atomicAdd(&uOffs[t], c); }
}

// ============================================================================
// Pass 1: exclusive scan of both bucket histograms (grid = 2 blocks,
// 1024 thr x 4 elem -> n <= 4096)
// ============================================================================
__global__ __launch_bounds__(1024) void scan_both(int* __restrict__ kgOffs,
                                                  int* __restrict__ kgCur,
                                                  int* __restrict__ uOffs,
                                                  int* __restrict__ uCur) {
    __shared__ int tsum[1024];
    int n     = (blockIdx.x == 0) ? NBK : NBU;
    int* offs = (blockIdx.x == 0) ? kgOffs : uOffs;
    int* cur  = (blockIdx.x == 0) ? kgCur : uCur;
    int tid = threadIdx.x;
    int base = tid * 4;
    int v0 = (base + 0 < n) ? offs[base + 0] : 0;
    int v1 = (base + 1 < n) ? offs[base + 1] : 0;
    int v2 = (base + 2 < n) ? offs[base + 2] : 0;
    int v3 = (base + 3 < n) ? offs[base + 3] : 0;
    int s = v0 + v1 + v2 + v3;
    tsum[tid] = s;
    __syncthreads();
    for (int off = 1; off < 1024; off <<= 1) {
        int t = (tid >= off) ? tsum[tid - off] : 0;
        __syncthreads();
        tsum[tid] += t;
        __syncthreads();
    }
    int excl = tsum[tid] - s;
    if (base < n)     { offs[base]     = excl;           cur[base]     = excl; }
    if (base + 1 < n) { int e = excl + v0;               offs[base + 1] = e; cur[base + 1] = e; }
    if (base + 2 < n) { int e = excl + v0 + v1;          offs[base + 2] = e; cur[base + 2] = e; }
    if (base + 3 < n) { int e = excl + v0 + v1 + v2;     offs[base + 3] = e; cur[base + 3] = e; }
    if (tid == 1023) offs[n] = tsum[1023];
}

// ============================================================================
// Pass 2: bucket partition with block-local reservation (coalesced-run writes)
// kg payload: tail(0..16) | type-1 (17..20) | rowlow (21..25)
// ============================================================================
__global__ __launch_bounds__(256) void scatter_kg(const int* __restrict__ head,
                                                  const int* __restrict__ tail,
                                                  const int* __restrict__ etype,
                                                  int* __restrict__ cur,
                                                  int* __restrict__ pay) {
    __shared__ int lh[NBK];
    __shared__ int lb[NBK];
    int tid = threadIdx.x;
    int base = blockIdx.x * CHUNK;
    for (int t = tid; t < NBK; t += 256) lh[t] = 0;
    __syncthreads();
#pragma unroll 4
    for (int j = 0; j < CHUNK / 256; ++j) {
        int i = base + j * 256 + tid;
        if (i < N_EDGES) atomicAdd(&lh[head[i] >> BSHIFT], 1);
    }
    __syncthreads();
    for (int t = tid; t < NBK; t += 256) {
        int c = lh[t];
        lb[t] = c ? atomicAdd(&cur[t], c) : 0;
        lh[t] = 0;
    }
    __syncthreads();
#pragma unroll 4
    for (int j = 0; j < CHUNK / 256; ++j) {
        int i = base + j * 256 + tid;
        if (i < N_EDGES) {
            int h = head[i];
            int b = h >> BSHIFT;
            int p = lb[b] + atomicAdd(&lh[b], 1);
            pay[p] = tail[i] | ((etype[i] - 1) << 17) | ((h & (BROWS - 1)) << 21);
        }
    }
}

// user payload: int2 { col(0..16)|rowlow(17..21), val_bits }
__global__ __launch_bounds__(256) void scatter_user(const int* __restrict__ urows,
                                                    const int* __restrict__ ucols,
                                                    const float* __restrict__ uvals,
                                                    int* __restrict__ cur,
                                                    int2* __restrict__ pay) {
    __shared__ int lh[NBU];
    __shared__ int lb[NBU];
    int tid = threadIdx.x;
    int base = blockIdx.x * CHUNK;
    for (int t = tid; t < NBU; t += 256) lh[t] = 0;
    __syncthreads();
#pragma unroll 4
    for (int j = 0; j < CHUNK / 256; ++j) {
        int i = base + j * 256 + tid;
        if (i < NNZ) atomicAdd(&lh[urows[i] >> BSHIFT], 1);
    }
    __syncthreads();
    for (int t = tid; t < NBU; t += 256) {
        int c = lh[t];
        lb[t] = c ? atomicAdd(&cur[t], c) : 0;
        lh[t] = 0;
    }
    __syncthreads();
#pragma unroll 4
    for (int j = 0; j < CHUNK / 256; ++j) {
        int i = base + j * 256 + tid;
        if (i < NNZ) {
            int r = urows[i];
            int b = r >> BSHIFT;
            int p = lb[b] + atomicAdd(&lh[b], 1);
            pay[p] = make_int2(ucols[i] | ((r & (BROWS - 1)) << 17),
                               __float_as_int(uvals[i]));
        }
    }
}

// ============================================================================
// Pass 3a: KG accumulate — one block (512 thr, 8 waves) per 32-row bucket,
// LDS f32 accumulators, mean-divide fused into epilogue.
// ============================================================================
__global__ __launch_bounds__(512) void acc_kg(const int* __restrict__ pay,
                                              const int* __restrict__ offs,
                                              const float* __restrict__ entity_emb,
                                              const float* __restrict__ weight,
                                              float* __restrict__ out) {
    __shared__ float acc[BROWS * EMB];
    __shared__ int cnt[BROWS];
    int tid = threadIdx.x, d = tid & 63, wv = tid >> 6;   // wv 0..7
    for (int t = tid; t < BROWS * EMB; t += 512) acc[t] = 0.f;
    if (tid < BROWS) cnt[tid] = 0;
    __syncthreads();
    int start = offs[blockIdx.x], end = offs[blockIdx.x + 1];
    int i = start + wv;
    for (; i + 24 < end; i += 32) {
        int v0 = pay[i], v1 = pay[i + 8], v2 = pay[i + 16], v3 = pay[i + 24];
        float a0 = entity_emb[(v0 & 0x1FFFF) * EMB + d] * weight[((v0 >> 17) & 15) * EMB + d];
        float a1 = entity_emb[(v1 & 0x1FFFF) * EMB + d] * weight[((v1 >> 17) & 15) * EMB + d];
        float a2 = entity_emb[(v2 & 0x1FFFF) * EMB + d] * weight[((v2 >> 17) & 15) * EMB + d];
        float a3 = entity_emb[(v3 & 0x1FFFF) * EMB + d] * weight[((v3 >> 17) & 15) * EMB + d];
        int r0 = (v0 >> 21) & (BROWS - 1), r1 = (v1 >> 21) & (BROWS - 1);
        int r2 = (v2 >> 21) & (BROWS - 1), r3 = (v3 >> 21) & (BROWS - 1);
        atomicAdd(&acc[r0 * EMB + d], a0);
        atomicAdd(&acc[r1 * EMB + d], a1);
        atomicAdd(&acc[r2 * EMB + d], a2);
        atomicAdd(&acc[r3 * EMB + d], a3);
        if (d == 0) {
            atomicAdd(&cnt[r0], 1); atomicAdd(&cnt[r1], 1);
            atomicAdd(&cnt[r2], 1); atomicAdd(&cnt[r3], 1);
        }
    }
    for (; i < end; i += 8) {
        int v = pay[i];
        float a = entity_emb[(v & 0x1FFFF) * EMB + d] * weight[((v >> 17) & 15) * EMB + d];
        int r = (v >> 21) & (BROWS - 1);
        atomicAdd(&acc[r * EMB + d], a);
        if (d == 0) atomicAdd(&cnt[r], 1);
    }
    __syncthreads();
    int rowbase = blockIdx.x * BROWS;
    for (int r = wv; r < BROWS; r += 8) {
        int gr = rowbase + r;
        if (gr < N_ENTITIES)
            out[gr * EMB + d] = acc[r * EMB + d] / fmaxf((float)cnt[r], 1.f);
    }
}

// ============================================================================
// Pass 3b: user accumulate + fused attention gating epilogue.
// ============================================================================
__global__ __launch_bounds__(512) void acc_user(const int2* __restrict__ pay,
                                                const int* __restrict__ offs,
                                                const float* __restrict__ entity_emb,
                                                const float* __restrict__ user_emb,
                                                const float* __restrict__ P,
                                                const float* __restrict__ cvec,
                                                const float* __restrict__ W_user_att,
                                                const float* __restrict__ b_user_att,
                                                const float* __restrict__ latent_new,
                                                float* __restrict__ out) {
    __shared__ float acc[BROWS * EMB];
    int tid = threadIdx.x, d = tid & 63, wv = tid >> 6;
    for (int t = tid; t < BROWS * EMB; t += 512) acc[t] = 0.f;
    __syncthreads();
    int start = offs[blockIdx.x], end = offs[blockIdx.x + 1];
    int i = start + wv;
    for (; i + 24 < end; i += 32) {
        int2 v0 = pay[i], v1 = pay[i + 8], v2 = pay[i + 16], v3 = pay[i + 24];
        float a0 = __int_as_float(v0.y) * entity_emb[(v0.x & 0x1FFFF) * EMB + d];
        float a1 = __int_as_float(v1.y) * entity_emb[(v1.x & 0x1FFFF) * EMB + d];
        float a2 = __int_as_float(v2.y) * entity_emb[(v2.x & 0x1FFFF) * EMB + d];
        float a3 = __int_as_float(v3.y) * entity_emb[(v3.x & 0x1FFFF) * EMB + d];
        atomicAdd(&acc[((v0.x >> 17) & (BROWS - 1)) * EMB + d], a0);
        atomicAdd(&acc[((v1.x >> 17) & (BROWS - 1)) * EMB + d], a1);
        atomicAdd(&acc[((v2.x >> 17) & (BROWS - 1)) * EMB + d], a2);
        atomicAdd(&acc[((v3.x >> 17) & (BROWS - 1)) * EMB + d], a3);
    }
    for (; i < end; i += 8) {
        int2 v = pay[i];
        float a = __int_as_float(v.y) * entity_emb[(v.x & 0x1FFFF) * EMB + d];
        atomicAdd(&acc[((v.x >> 17) & (BROWS - 1)) * EMB + d], a);
    }
    __syncthreads();

    int rowbase = blockIdx.x * BROWS;
    for (int r = wv; r < BROWS; r += 8) {
        int gr = rowbase + r;
        if (gr >= N_USERS) continue;   // wave-uniform
        float ue = user_emb[gr * EMB + d];
        float s[8];
#pragma unroll
        for (int f = 0; f < 8; ++f) s[f] = ue * P[d * 8 + f];
#pragma unroll
        for (int off = 32; off; off >>= 1) {
#pragma unroll
            for (int f = 0; f < 8; ++f) s[f] += __shfl_xor(s[f], off, 64);
        }
#pragma unroll
        for (int f = 0; f < 8; ++f) s[f] += cvec[f];

        float att[8];
        float mx = -1e30f;
#pragma unroll
        for (int k = 0; k < 8; ++k) {
            float a = b_user_att[k];
#pragma unroll
            for (int j = 0; j < 8; ++j) a += s[j] * W_user_att[k * 8 + j];
            a = a > 0.f ? a : SLOPE * a;
            att[k] = a;
            mx = fmaxf(mx, a);
        }
        float sum = 0.f;
#pragma unroll
        for (int k = 0; k < 8; ++k) { att[k] = __expf(att[k] - mx); sum += att[k]; }
        float inv = 1.f / sum;
        float g = 0.f;
#pragma unroll
        for (int f = 0; f < 8; ++f) g += att[f] * inv * latent_new[f * EMB + d];
        out[gr * EMB + d] = acc[r * EMB + d] * (1.f + g);
    }
}

// ============================================================================
// Small dense math (one wave): latent_new, P = W1^T·lat1^T, c = b1·lat1^T
// ============================================================================
__global__ void small_dense(const float* __restrict__ latent_emb,
                            const float* __restrict__ weight,
                            const float* __restrict__ W_weight_att,
                            const float* __restrict__ b_weight_att,
                            const float* __restrict__ W1,
                            const float* __restrict__ b1,
                            const float* __restrict__ W2,
                            const float* __restrict__ b2,
                            float* __restrict__ P_out,
                            float* __restrict__ c_out,
                            float* __restrict__ latent_new_out) {
    __shared__ float lat1[8 * 64];
    __shared__ float lat2[8 * 64];
    __shared__ float wl2[16 * 64];
    __shared__ float srp[8 * 16];
    __shared__ float soft[8 * 16];
    int l = threadIdx.x;  // 0..63

    for (int f = 0; f < 8; ++f) {
        float a1 = b1[l], a2 = b2[l];
        for (int k = 0; k < 64; ++k) {
            float le = latent_emb[f * 64 + k];
            a1 += le * W1[l * 64 + k];
            a2 += le * W2[l * 64 + k];
        }
        lat1[f * 64 + l] = a1;
        lat2[f * 64 + l] = a2;
    }
    for (int r = 0; r < 16; ++r) {
        float a = b2[l];
        for (int k = 0; k < 64; ++k) a += weight[r * 64 + k] * W2[l * 64 + k];
        wl2[r * 64 + l] = a;
    }
    __syncthreads();

    for (int f = 0; f < 8; ++f) {
        float p = 0.f;
        for (int d = 0; d < 64; ++d) p += W1[d * 64 + l] * lat1[f * 64 + d];
        P_out[l * 8 + f] = p;
    }
    if (l < 8) {
        float cc = 0.f;
        for (int d = 0; d < 64; ++d) cc += b1[d] * lat1[l * 64 + d];
        c_out[l] = cc;
    }
    for (int idx = l; idx < 128; idx += 64) {
        int f = idx >> 4, r = idx & 15;
        float a = 0.f;
        for (int d = 0; d < 64; ++d) a += lat2[f * 64 + d] * wl2[r * 64 + d];
        srp[idx] = a;
    }
    __syncthreads();

    if (l < 8) {
        int f = l;
        float att[16];
        float mx = -1e30f;
        for (int k = 0; k < 16; ++k) {
            float a = b_weight_att[k];
            for (int j = 0; j < 16; ++j) a += srp[f * 16 + j] * W_weight_att[k * 16 + j];
            a = a > 0.f ? a : SLOPE * a;
            att[k] = a;
            mx = fmaxf(mx, a);
        }
        float s = 0.f;
        for (int k = 0; k < 16; ++k) { att[k] = expf(att[k] - mx); s += att[k]; }
        float inv = 1.f / s;
        for (int k = 0; k < 16; ++k) soft[f * 16 + k] = att[k] * inv;
    }
    __syncthreads();

    for (int f = 0; f < 8; ++f) {
        float a = 0.f;
        for (int r = 0; r < 16; ++r) a += soft[f * 16 + r] * weight[r * 64 + l];
        latent_new_out[f * 64 + l] = a;
    }
}

// ============================================================================
// Fallback atomic path (verified) — only if ws too small
// ============================================================================
__global__ void kg_scatter(const int* __restrict__ head, const int* __restrict__ tail,
                           const int* __restrict__ etype,
                           const float* __restrict__ entity_emb,
                           const float* __restrict__ weight,
                           float* __restrict__ sums, float* __restrict__ cnt) {
    int gid = blockIdx.x * blockDim.x + threadIdx.x;
    int e = gid >> 6, d = threadIdx.x & 63;
    if (e >= N_EDGES) return;
    int h = head[e], t = tail[e], w = etype[e] - 1;
    float v = entity_emb[t * EMB + d] * weight[w * EMB + d];
    unsafeAtomicAdd(&sums[h * EMB + d], v);
    if (d == 0) unsafeAtomicAdd(&cnt[h], 1.0f);
}

__global__ void user_scatter(const int* __restrict__ rows, const int* __restrict__ cols,
                             const float* __restrict__ vals,
                             const float* __restrict__ entity_emb,
                             float* __restrict__ user_sums) {
    int gid = blockIdx.x * blockDim.x + threadIdx.x;
    int e = gid >> 6, d = threadIdx.x & 63;
    if (e >= NNZ) return;
    float v = vals[e] * entity_emb[cols[e] * EMB + d];
    unsafeAtomicAdd(&user_sums[rows[e] * EMB + d], v);
}

__global__ void entity_div(float* __restrict__ ent, const float* __restrict__ cnt) {
    int gid = blockIdx.x * blockDim.x + threadIdx.x;
    if (gid >= N_ENTITIES * EMB) return;
    float c = cnt[gid >> 6];
    ent[gid] = ent[gid] / fmaxf(c, 1.0f);
}

__global__ void user_finalize(const float* __restrict__ user_emb,
                              const float* __restrict__ P,
                              const float* __restrict__ c,
                              const float* __restrict__ W_user_att,
                              const float* __restrict__ b_user_att,
                              const float* __restrict__ latent_new,
                              float* __restrict__ user_out) {
    int gid = blockIdx.x * blockDim.x + threadIdx.x;
    int u = gid >> 6, lane = threadIdx.x & 63;
    if (u >= N_USERS) return;
    float ue = user_emb[u * 64 + lane];
    float s[8];
#pragma unroll
    for (int f = 0; f < 8; ++f) s[f] = ue * P[lane * 8 + f];
#pragma unroll
    for (int off = 32; off; off >>= 1)
#pragma unroll
        for (int f = 0; f < 8; ++f) s[f] += __shfl_xor(s[f], off, 64);
#pragma unroll
    for (int f = 0; f < 8; ++f) s[f] += c[f];
    float att[8], mx = -1e30f;
#pragma unroll
    for (int k = 0; k < 8; ++k) {
        float a = b_user_att[k];
#pragma unroll
        for (int j = 0; j < 8; ++j) a += s[j] * W_user_att[k * 8 + j];
        a = a > 0.f ? a : SLOPE * a;
        att[k] = a;
        mx = fmaxf(mx, a);
    }
    float sum = 0.f;
#pragma unroll
    for (int k = 0; k < 8; ++k) { att[k] = expf(att[k] - mx); sum += att[k]; }
    float inv = 1.f / sum, g = 0.f;
#pragma unroll
    for (int f = 0; f < 8; ++f) g += att[f] * inv * latent_new[f * 64 + lane];
    float ua = user_out[u * 64 + lane];
    user_out[u * 64 + lane] = ua * (1.f + g);
}

extern "C" void kernel_launch(void* const* d_in, const int* in_sizes, int n_in,
                              void* d_out, int out_size, void* d_ws, size_t ws_size,
                              hipStream_t stream) {
    const float* entity_emb   = (const float*)d_in[0];
    const float* user_emb     = (const float*)d_in[1];
    const float* latent_emb   = (const float*)d_in[2];
    const int*   edge_index   = (const int*)d_in[3];
    const int*   edge_type    = (const int*)d_in[4];
    const int*   irows        = (const int*)d_in[5];
    const int*   icols        = (const int*)d_in[6];
    const float* ivals        = (const float*)d_in[7];
    const float* weight       = (const float*)d_in[8];
    const float* W_user_att   = (const float*)d_in[10];
    const float* b_user_att   = (const float*)d_in[11];
    const float* W_weight_att = (const float*)d_in[12];
    const float* b_weight_att = (const float*)d_in[13];
    const float* W1           = (const float*)d_in[14];
    const float* b1           = (const float*)d_in[15];
    const float* W2           = (const float*)d_in[16];
    const float* b2           = (const float*)d_in[17];

    float* out      = (float*)d_out;
    float* ent_out  = out;
    float* user_out = out + (size_t)N_ENTITIES * EMB;
    float* lat_out  = user_out + (size_t)N_USERS * EMB;

    const int* head = edge_index;
    const int* tail = edge_index + N_EDGES;

    // ---- workspace layout ----
    int* ws_i = (int*)d_ws;
    int*   kgOffs = ws_i;                       // NBK+1 = 3126
    int*   uOffs  = kgOffs + (NBK + 1);         // NBU+1 = 1564
    int*   kgCur  = uOffs + (NBU + 1);          // 3125
    int*   uCur   = kgCur + NBK;                // 1563
    int*   kgPay  = uCur + NBU;                 // 2,000,000
    int2*  uPay   = (int2*)(kgPay + N_EDGES);   // 2,000,000 int2 (8B-aligned)
    float* Pbuf   = (float*)(uPay + NNZ);       // 512
    float* cbuf   = Pbuf + 64 * 8;              // 8
    size_t need_bytes = (size_t)((NBK + 1) + (NBU + 1) + NBK + NBU +
                                 N_EDGES + 2 * (size_t)NNZ + 512 + 8) * 4;

    if (ws_size >= need_bytes) {
        // zero both histogram regions in one memset (they are contiguous)
        hipMemsetAsync(kgOffs, 0, (size_t)((NBK + 1) + (NBU + 1)) * sizeof(int), stream);

        hist_both<<<PB, 256, 0, stream>>>(head, irows, kgOffs, uOffs);
        scan_both<<<2, 1024, 0, stream>>>(kgOffs, kgCur, uOffs, uCur);
        scatter_kg<<<PB, 256, 0, stream>>>(head, tail, edge_type, kgCur, kgPay);
        scatter_user<<<PB, 256, 0, stream>>>(irows, icols, ivals, uCur, uPay);
        small_dense<<<1, 64, 0, stream>>>(latent_emb, weight, W_weight_att,
                                          b_weight_att, W1, b1, W2, b2,
                                          Pbuf, cbuf, lat_out);
        acc_kg<<<NBK, 512, 0, stream>>>(kgPay, kgOffs, entity_emb, weight, ent_out);
        acc_user<<<NBU, 512, 0, stream>>>(uPay, uOffs, entity_emb, user_emb,
                                          Pbuf, cbuf, W_user_att, b_user_att,
                                          lat_out, user_out);
    } else {
        // ---------- fallback atomic path ----------
        float* cnt   = (float*)d_ws;
        float* Pbuf2 = cnt + N_ENTITIES;
        float* cbuf2 = Pbuf2 + 64 * 8;
        hipMemsetAsync(ent_out, 0,
                       (size_t)(N_ENTITIES + N_USERS) * EMB * sizeof(float), stream);
        hipMemsetAsync(cnt, 0, N_ENTITIES * sizeof(float), stream);
        int blocks_edges = (N_EDGES * 64) / 256;
        kg_scatter<<<blocks_edges, 256, 0, stream>>>(head, tail, edge_type, entity_emb,
                                                     weight, ent_out, cnt);
        user_scatter<<<blocks_edges, 256, 0, stream>>>(irows, icols, ivals, entity_emb,
                                                       user_out);
        small_dense<<<1, 64, 0, stream>>>(latent_emb, weight, W_weight_att,
                                          b_weight_att, W1, b1, W2, b2,
                                          Pbuf2, cbuf2, lat_out);
        user_finalize<<<(N_USERS * 64) / 256, 256, 0, stream>>>(user_emb, Pbuf2, cbuf2,
                                                                W_user_att, b_user_att,
                                                                lat_out, user_out);
        entity_div<<<(N_ENTITIES * EMB) / 256, 256, 0, stream>>>(ent_out, cnt);
    }
}

// Round 5
// 469.186 us; speedup vs baseline: 4.4930x; 3.9007x over previous
//
#include <hip/hip_runtime.h>
#include <hip/hip_bf16.h>

#define N_USERS    50000
#define N_ENTITIES 100000
#define EMB        64
#define N_EDGES    2000000
#define NNZ        2000000
#define SLOPE      0.2f

// ---- bucket geometry -------------------------------------------------------
#define KROWS   256                 // entity rows per bucket
#define KSHIFT  8
#define NBK     391                 // ceil(100000/256)
#define UROWS   128                 // user rows per bucket
#define USHIFT  7
#define NBU     391                 // ceil(50000/128)
#define CAPK    8192                // LDS payload capacity (kg, 4 B)  = 32 KB
#define CAPU    7680                // LDS payload capacity (user, 8 B)= 60 KB
#define CHUNK   8192                // edges per partition block
#define PB      ((N_EDGES + CHUNK - 1) / CHUNK)      // 245

// ============================================================================
// Pass 0: fused bucket histograms (LDS-privatized)
// ============================================================================
__global__ __launch_bounds__(512) void hist_both(const int* __restrict__ head,
                                                 const int* __restrict__ urows,
                                                 int* __restrict__ kgOffs,
                                                 int* __restrict__ uOffs) {
    __shared__ int lhk[NBK];
    __shared__ int lhu[NBU];
    int tid = threadIdx.x;
    for (int t = tid; t < NBK; t += 512) lhk[t] = 0;
    for (int t = tid; t < NBU; t += 512) lhu[t] = 0;
    __syncthreads();
    int base = blockIdx.x * CHUNK;
#pragma unroll 4
    for (int j = 0; j < CHUNK / 512; ++j) {
        int i = base + j * 512 + tid;
        if (i < N_EDGES) atomicAdd(&lhk[head[i] >> KSHIFT], 1);
        if (i < NNZ)     atomicAdd(&lhu[urows[i] >> USHIFT], 1);
    }
    __syncthreads();
    for (int t = tid; t < NBK; t += 512) { int c = lhk[t]; if (c) atomicAdd(&kgOffs[t], c); }
    for (int t = tid; t < NBU; t += 512) { int c = lhu[t]; if (c) atomicAdd(&uOffs[t], c); }
}

// ============================================================================
// Pass 1: exclusive scan of both bucket histograms (grid = 2 blocks)
// ============================================================================
__global__ __launch_bounds__(512) void scan_both(int* __restrict__ kgOffs,
                                                 int* __restrict__ kgCur,
                                                 int* __restrict__ uOffs,
                                                 int* __restrict__ uCur) {
    __shared__ int tsum[512];
    int n     = (blockIdx.x == 0) ? NBK : NBU;   // both 391
    int* offs = (blockIdx.x == 0) ? kgOffs : uOffs;
    int* cur  = (blockIdx.x == 0) ? kgCur  : uCur;
    int tid = threadIdx.x;
    int v = (tid < n) ? offs[tid] : 0;
    tsum[tid] = v;
    __syncthreads();
    for (int off = 1; off < 512; off <<= 1) {
        int t = (tid >= off) ? tsum[tid - off] : 0;
        __syncthreads();
        tsum[tid] += t;
        __syncthreads();
    }
    if (tid < n) { int e = tsum[tid] - v; offs[tid] = e; cur[tid] = e; }
    if (tid == n - 1) offs[n] = tsum[tid];
}

// ============================================================================
// Pass 2: bucket partition with block-local reservation (coalesced-run writes)
// kg payload: tail(0..16) | type-1 (17..20) | rowlow (21..28)
// ============================================================================
__global__ __launch_bounds__(512) void scatter_kg(const int* __restrict__ head,
                                                  const int* __restrict__ tail,
                                                  const int* __restrict__ etype,
                                                  int* __restrict__ cur,
                                                  int* __restrict__ pay) {
    __shared__ int lh[NBK];
    __shared__ int lb[NBK];
    int tid = threadIdx.x;
    int base = blockIdx.x * CHUNK;
    for (int t = tid; t < NBK; t += 512) lh[t] = 0;
    __syncthreads();
#pragma unroll 4
    for (int j = 0; j < CHUNK / 512; ++j) {
        int i = base + j * 512 + tid;
        if (i < N_EDGES) atomicAdd(&lh[head[i] >> KSHIFT], 1);
    }
    __syncthreads();
    for (int t = tid; t < NBK; t += 512) {
        int c = lh[t];
        lb[t] = c ? atomicAdd(&cur[t], c) : 0;
        lh[t] = 0;
    }
    __syncthreads();
#pragma unroll 4
    for (int j = 0; j < CHUNK / 512; ++j) {
        int i = base + j * 512 + tid;
        if (i < N_EDGES) {
            int h = head[i];
            int b = h >> KSHIFT;
            int p = lb[b] + atomicAdd(&lh[b], 1);
            pay[p] = tail[i] | ((etype[i] - 1) << 17) | ((h & (KROWS - 1)) << 21);
        }
    }
}

// user payload: int2 { col(0..16) | rowlow(17..23), val_bits }
__global__ __launch_bounds__(512) void scatter_user(const int* __restrict__ urows,
                                                    const int* __restrict__ ucols,
                                                    const float* __restrict__ uvals,
                                                    int* __restrict__ cur,
                                                    int2* __restrict__ pay) {
    __shared__ int lh[NBU];
    __shared__ int lb[NBU];
    int tid = threadIdx.x;
    int base = blockIdx.x * CHUNK;
    for (int t = tid; t < NBU; t += 512) lh[t] = 0;
    __syncthreads();
#pragma unroll 4
    for (int j = 0; j < CHUNK / 512; ++j) {
        int i = base + j * 512 + tid;
        if (i < NNZ) atomicAdd(&lh[urows[i] >> USHIFT], 1);
    }
    __syncthreads();
    for (int t = tid; t < NBU; t += 512) {
        int c = lh[t];
        lb[t] = c ? atomicAdd(&cur[t], c) : 0;
        lh[t] = 0;
    }
    __syncthreads();
#pragma unroll 4
    for (int j = 0; j < CHUNK / 512; ++j) {
        int i = base + j * 512 + tid;
        if (i < NNZ) {
            int r = urows[i];
            int b = r >> USHIFT;
            int p = lb[b] + atomicAdd(&lh[b], 1);
            pay[p] = make_int2(ucols[i] | ((r & (UROWS - 1)) << 17),
                               __float_as_int(uvals[i]));
        }
    }
}

// ============================================================================
// Pass 3a: KG accumulate — one 1024-thr block per 256-row bucket.
// In-LDS counting sort to exact row, then per-wave REGISTER accumulation
// (no LDS atomics in the gather loop). Mean-divide fused.
// ============================================================================
__global__ __launch_bounds__(1024) void acc_kg(const int* __restrict__ pay,
                                               const int* __restrict__ offs,
                                               const float* __restrict__ entity_emb,
                                               const float* __restrict__ weight,
                                               float* __restrict__ out) {
    __shared__ int spay[CAPK];      // 32 KB row-sorted payload
    __shared__ int lcnt[KROWS];
    __shared__ int lofs[KROWS + 1];
    __shared__ int sc[KROWS];
    int t = threadIdx.x, d = t & 63, wv = t >> 6;    // wv 0..15
    int start = offs[blockIdx.x], end = offs[blockIdx.x + 1];
    int n = end - start; if (n > CAPK) n = CAPK;

    if (t < KROWS) lcnt[t] = 0;
    __syncthreads();
    for (int i = t; i < n; i += 1024)
        atomicAdd(&lcnt[(pay[start + i] >> 21) & (KROWS - 1)], 1);
    __syncthreads();
    if (t < KROWS) sc[t] = lcnt[t];
    __syncthreads();
    for (int off = 1; off < KROWS; off <<= 1) {
        int v = (t < KROWS && t >= off) ? sc[t - off] : 0;
        __syncthreads();
        if (t < KROWS) sc[t] += v;
        __syncthreads();
    }
    if (t < KROWS) { int e = sc[t] - lcnt[t]; lofs[t] = e; lcnt[t] = e; }
    if (t == 0) lofs[KROWS] = n;
    __syncthreads();
    for (int i = t; i < n; i += 1024) {
        int v = pay[start + i];
        int p = atomicAdd(&lcnt[(v >> 21) & (KROWS - 1)], 1);
        spay[p] = v;
    }
    __syncthreads();

    int rowbase = blockIdx.x * KROWS;
    for (int rr = 0; rr < KROWS / 16; ++rr) {
        int r = wv * (KROWS / 16) + rr;
        int gr = rowbase + r;
        if (gr >= N_ENTITIES) break;          // wave-uniform; last block only
        int s0 = lofs[r], e0 = lofs[r + 1];
        int cnt = e0 - s0;
        float acc = 0.f;
        int i = s0;
        for (; i + 3 < e0; i += 4) {
            int v0 = spay[i], v1 = spay[i + 1], v2 = spay[i + 2], v3 = spay[i + 3];
            float a0 = entity_emb[(v0 & 0x1FFFF) * EMB + d] * weight[((v0 >> 17) & 15) * EMB + d];
            float a1 = entity_emb[(v1 & 0x1FFFF) * EMB + d] * weight[((v1 >> 17) & 15) * EMB + d];
            float a2 = entity_emb[(v2 & 0x1FFFF) * EMB + d] * weight[((v2 >> 17) & 15) * EMB + d];
            float a3 = entity_emb[(v3 & 0x1FFFF) * EMB + d] * weight[((v3 >> 17) & 15) * EMB + d];
            acc += (a0 + a1) + (a2 + a3);
        }
        for (; i < e0; ++i) {
            int v = spay[i];
            acc += entity_emb[(v & 0x1FFFF) * EMB + d] * weight[((v >> 17) & 15) * EMB + d];
        }
        // overflow tail (statistically never taken; capacity = mean + 36 sigma)
        for (int j = start + CAPK; j < end; ++j) {
            int v = pay[j];
            if (((v >> 21) & (KROWS - 1)) == r) {
                acc += entity_emb[(v & 0x1FFFF) * EMB + d] * weight[((v >> 17) & 15) * EMB + d];
                ++cnt;
            }
        }
        out[gr * EMB + d] = acc / fmaxf((float)cnt, 1.f);
    }
}

// ============================================================================
// Pass 3b: user accumulate + fused attention gating — one 1024-thr block per
// 128-row bucket, same in-LDS sort + register-accumulate structure.
// ============================================================================
__global__ __launch_bounds__(1024) void acc_user(const int2* __restrict__ pay,
                                                 const int* __restrict__ offs,
                                                 const float* __restrict__ entity_emb,
                                                 const float* __restrict__ user_emb,
                                                 const float* __restrict__ P,
                                                 const float* __restrict__ cvec,
                                                 const float* __restrict__ W_user_att,
                                                 const float* __restrict__ b_user_att,
                                                 const float* __restrict__ latent_new,
                                                 float* __restrict__ out) {
    __shared__ int2 spay[CAPU];     // 60 KB row-sorted payload
    __shared__ int lcnt[UROWS];
    __shared__ int lofs[UROWS + 1];
    __shared__ int sc[UROWS];
    int t = threadIdx.x, d = t & 63, wv = t >> 6;    // wv 0..15
    int start = offs[blockIdx.x], end = offs[blockIdx.x + 1];
    int n = end - start; if (n > CAPU) n = CAPU;

    if (t < UROWS) lcnt[t] = 0;
    __syncthreads();
    for (int i = t; i < n; i += 1024)
        atomicAdd(&lcnt[(pay[start + i].x >> 17) & (UROWS - 1)], 1);
    __syncthreads();
    if (t < UROWS) sc[t] = lcnt[t];
    __syncthreads();
    for (int off = 1; off < UROWS; off <<= 1) {
        int v = (t < UROWS && t >= off) ? sc[t - off] : 0;
        __syncthreads();
        if (t < UROWS) sc[t] += v;
        __syncthreads();
    }
    if (t < UROWS) { int e = sc[t] - lcnt[t]; lofs[t] = e; lcnt[t] = e; }
    if (t == 0) lofs[UROWS] = n;
    __syncthreads();
    for (int i = t; i < n; i += 1024) {
        int2 v = pay[start + i];
        int p = atomicAdd(&lcnt[(v.x >> 17) & (UROWS - 1)], 1);
        spay[p] = v;
    }
    __syncthreads();

    int rowbase = blockIdx.x * UROWS;
    for (int rr = 0; rr < UROWS / 16; ++rr) {
        int r = wv * (UROWS / 16) + rr;
        int gr = rowbase + r;
        if (gr >= N_USERS) break;             // wave-uniform; last block only
        int s0 = lofs[r], e0 = lofs[r + 1];
        float acc = 0.f;
        int i = s0;
        for (; i + 3 < e0; i += 4) {
            int2 v0 = spay[i], v1 = spay[i + 1], v2 = spay[i + 2], v3 = spay[i + 3];
            float a0 = __int_as_float(v0.y) * entity_emb[(v0.x & 0x1FFFF) * EMB + d];
            float a1 = __int_as_float(v1.y) * entity_emb[(v1.x & 0x1FFFF) * EMB + d];
            float a2 = __int_as_float(v2.y) * entity_emb[(v2.x & 0x1FFFF) * EMB + d];
            float a3 = __int_as_float(v3.y) * entity_emb[(v3.x & 0x1FFFF) * EMB + d];
            acc += (a0 + a1) + (a2 + a3);
        }
        for (; i < e0; ++i) {
            int2 v = spay[i];
            acc += __int_as_float(v.y) * entity_emb[(v.x & 0x1FFFF) * EMB + d];
        }
        for (int j = start + CAPU; j < end; ++j) {   // overflow tail (never taken)
            int2 v = pay[j];
            if (((v.x >> 17) & (UROWS - 1)) == r)
                acc += __int_as_float(v.y) * entity_emb[(v.x & 0x1FFFF) * EMB + d];
        }

        // fused attention gating epilogue for this row
        float ue = user_emb[gr * EMB + d];
        float s[8];
#pragma unroll
        for (int f = 0; f < 8; ++f) s[f] = ue * P[d * 8 + f];
#pragma unroll
        for (int off = 32; off; off >>= 1) {
#pragma unroll
            for (int f = 0; f < 8; ++f) s[f] += __shfl_xor(s[f], off, 64);
        }
#pragma unroll
        for (int f = 0; f < 8; ++f) s[f] += cvec[f];
        float att[8];
        float mx = -1e30f;
#pragma unroll
        for (int k = 0; k < 8; ++k) {
            float a = b_user_att[k];
#pragma unroll
            for (int j = 0; j < 8; ++j) a += s[j] * W_user_att[k * 8 + j];
            a = a > 0.f ? a : SLOPE * a;
            att[k] = a;
            mx = fmaxf(mx, a);
        }
        float sum = 0.f;
#pragma unroll
        for (int k = 0; k < 8; ++k) { att[k] = __expf(att[k] - mx); sum += att[k]; }
        float inv = 1.f / sum;
        float g = 0.f;
#pragma unroll
        for (int f = 0; f < 8; ++f) g += att[f] * inv * latent_new[f * EMB + d];
        out[gr * EMB + d] = acc * (1.f + g);
    }
}

// ============================================================================
// Small dense math (one wave): latent_new, P = W1^T·lat1^T, c = b1·lat1^T
// ============================================================================
__global__ void small_dense(const float* __restrict__ latent_emb,
                            const float* __restrict__ weight,
                            const float* __restrict__ W_weight_att,
                            const float* __restrict__ b_weight_att,
                            const float* __restrict__ W1,
                            const float* __restrict__ b1,
                            const float* __restrict__ W2,
                            const float* __restrict__ b2,
                            float* __restrict__ P_out,
                            float* __restrict__ c_out,
                            float* __restrict__ latent_new_out) {
    __shared__ float lat1[8 * 64];
    __shared__ float lat2[8 * 64];
    __shared__ float wl2[16 * 64];
    __shared__ float srp[8 * 16];
    __shared__ float soft[8 * 16];
    int l = threadIdx.x;  // 0..63

    for (int f = 0; f < 8; ++f) {
        float a1 = b1[l], a2 = b2[l];
        for (int k = 0; k < 64; ++k) {
            float le = latent_emb[f * 64 + k];
            a1 += le * W1[l * 64 + k];
            a2 += le * W2[l * 64 + k];
        }
        lat1[f * 64 + l] = a1;
        lat2[f * 64 + l] = a2;
    }
    for (int r = 0; r < 16; ++r) {
        float a = b2[l];
        for (int k = 0; k < 64; ++k) a += weight[r * 64 + k] * W2[l * 64 + k];
        wl2[r * 64 + l] = a;
    }
    __syncthreads();

    for (int f = 0; f < 8; ++f) {
        float p = 0.f;
        for (int d = 0; d < 64; ++d) p += W1[d * 64 + l] * lat1[f * 64 + d];
        P_out[l * 8 + f] = p;
    }
    if (l < 8) {
        float cc = 0.f;
        for (int d = 0; d < 64; ++d) cc += b1[d] * lat1[l * 64 + d];
        c_out[l] = cc;
    }
    for (int idx = l; idx < 128; idx += 64) {
        int f = idx >> 4, r = idx & 15;
        float a = 0.f;
        for (int d = 0; d < 64; ++d) a += lat2[f * 64 + d] * wl2[r * 64 + d];
        srp[idx] = a;
    }
    __syncthreads();

    if (l < 8) {
        int f = l;
        float att[16];
        float mx = -1e30f;
        for (int k = 0; k < 16; ++k) {
            float a = b_weight_att[k];
            for (int j = 0; j < 16; ++j) a += srp[f * 16 + j] * W_weight_att[k * 16 + j];
            a = a > 0.f ? a : SLOPE * a;
            att[k] = a;
            mx = fmaxf(mx, a);
        }
        float s = 0.f;
        for (int k = 0; k < 16; ++k) { att[k] = expf(att[k] - mx); s += att[k]; }
        float inv = 1.f / s;
        for (int k = 0; k < 16; ++k) soft[f * 16 + k] = att[k] * inv;
    }
    __syncthreads();

    for (int f = 0; f < 8; ++f) {
        float a = 0.f;
        for (int r = 0; r < 16; ++r) a += soft[f * 16 + r] * weight[r * 64 + l];
        latent_new_out[f * 64 + l] = a;
    }
}

// ============================================================================
// Fallback atomic path (verified) — only if ws too small
// ============================================================================
__global__ void kg_scatter(const int* __restrict__ head, const int* __restrict__ tail,
                           const int* __restrict__ etype,
                           const float* __restrict__ entity_emb,
                           const float* __restrict__ weight,
                           float* __restrict__ sums, float* __restrict__ cnt) {
    int gid = blockIdx.x * blockDim.x + threadIdx.x;
    int e = gid >> 6, d = threadIdx.x & 63;
    if (e >= N_EDGES) return;
    int h = head[e], t = tail[e], w = etype[e] - 1;
    float v = entity_emb[t * EMB + d] * weight[w * EMB + d];
    unsafeAtomicAdd(&sums[h * EMB + d], v);
    if (d == 0) unsafeAtomicAdd(&cnt[h], 1.0f);
}

__global__ void user_scatter(const int* __restrict__ rows, const int* __restrict__ cols,
                             const float* __restrict__ vals,
                             const float* __restrict__ entity_emb,
                             float* __restrict__ user_sums) {
    int gid = blockIdx.x * blockDim.x + threadIdx.x;
    int e = gid >> 6, d = threadIdx.x & 63;
    if (e >= NNZ) return;
    float v = vals[e] * entity_emb[cols[e] * EMB + d];
    unsafeAtomicAdd(&user_sums[rows[e] * EMB + d], v);
}

__global__ void entity_div(float* __restrict__ ent, const float* __restrict__ cnt) {
    int gid = blockIdx.x * blockDim.x + threadIdx.x;
    if (gid >= N_ENTITIES * EMB) return;
    float c = cnt[gid >> 6];
    ent[gid] = ent[gid] / fmaxf(c, 1.0f);
}

__global__ void user_finalize(const float* __restrict__ user_emb,
                              const float* __restrict__ P,
                              const float* __restrict__ c,
                              const float* __restrict__ W_user_att,
                              const float* __restrict__ b_user_att,
                              const float* __restrict__ latent_new,
                              float* __restrict__ user_out) {
    int gid = blockIdx.x * blockDim.x + threadIdx.x;
    int u = gid >> 6, lane = threadIdx.x & 63;
    if (u >= N_USERS) return;
    float ue = user_emb[u * 64 + lane];
    float s[8];
#pragma unroll
    for (int f = 0; f < 8; ++f) s[f] = ue * P[lane * 8 + f];
#pragma unroll
    for (int off = 32; off; off >>= 1)
#pragma unroll
        for (int f = 0; f < 8; ++f) s[f] += __shfl_xor(s[f], off, 64);
#pragma unroll
    for (int f = 0; f < 8; ++f) s[f] += c[f];
    float att[8], mx = -1e30f;
#pragma unroll
    for (int k = 0; k < 8; ++k) {
        float a = b_user_att[k];
#pragma unroll
        for (int j = 0; j < 8; ++j) a += s[j] * W_user_att[k * 8 + j];
        a = a > 0.f ? a : SLOPE * a;
        att[k] = a;
        mx = fmaxf(mx, a);
    }
    float sum = 0.f;
#pragma unroll
    for (int k = 0; k < 8; ++k) { att[k] = expf(att[k] - mx); sum += att[k]; }
    float inv = 1.f / sum, g = 0.f;
#pragma unroll
    for (int f = 0; f < 8; ++f) g += att[f] * inv * latent_new[f * 64 + lane];
    float ua = user_out[u * 64 + lane];
    user_out[u * 64 + lane] = ua * (1.f + g);
}

extern "C" void kernel_launch(void* const* d_in, const int* in_sizes, int n_in,
                              void* d_out, int out_size, void* d_ws, size_t ws_size,
                              hipStream_t stream) {
    const float* entity_emb   = (const float*)d_in[0];
    const float* user_emb     = (const float*)d_in[1];
    const float* latent_emb   = (const float*)d_in[2];
    const int*   edge_index   = (const int*)d_in[3];
    const int*   edge_type    = (const int*)d_in[4];
    const int*   irows        = (const int*)d_in[5];
    const int*   icols        = (const int*)d_in[6];
    const float* ivals        = (const float*)d_in[7];
    const float* weight       = (const float*)d_in[8];
    const float* W_user_att   = (const float*)d_in[10];
    const float* b_user_att   = (const float*)d_in[11];
    const float* W_weight_att = (const float*)d_in[12];
    const float* b_weight_att = (const float*)d_in[13];
    const float* W1           = (const float*)d_in[14];
    const float* b1           = (const float*)d_in[15];
    const float* W2           = (const float*)d_in[16];
    const float* b2           = (const float*)d_in[17];

    float* out      = (float*)d_out;
    float* ent_out  = out;
    float* user_out = out + (size_t)N_ENTITIES * EMB;
    float* lat_out  = user_out + (size_t)N_USERS * EMB;

    const int* head = edge_index;
    const int* tail = edge_index + N_EDGES;

    // ---- workspace layout ----
    int* ws_i = (int*)d_ws;
    int*   kgOffs = ws_i;                       // NBK+1 = 392
    int*   uOffs  = kgOffs + (NBK + 1);         // NBU+1 = 392
    int*   kgCur  = uOffs + (NBU + 1);          // 391
    int*   uCur   = kgCur + NBK;                // 391
    int*   kgPay  = uCur + NBU;                 // 2,000,000 int
    int2*  uPay   = (int2*)(kgPay + N_EDGES);   // 2,000,000 int2 (8 B aligned)
    float* Pbuf   = (float*)(uPay + NNZ);       // 512
    float* cbuf   = Pbuf + 64 * 8;              // 8
    size_t need_bytes = (size_t)((NBK + 1) + (NBU + 1) + NBK + NBU +
                                 N_EDGES + 2 * (size_t)NNZ + 512 + 8) * 4;

    if (ws_size >= need_bytes) {
        // zero both histogram regions in one memset (contiguous)
        hipMemsetAsync(kgOffs, 0, (size_t)((NBK + 1) + (NBU + 1)) * sizeof(int), stream);

        hist_both<<<PB, 512, 0, stream>>>(head, irows, kgOffs, uOffs);
        scan_both<<<2, 512, 0, stream>>>(kgOffs, kgCur, uOffs, uCur);
        scatter_kg<<<PB, 512, 0, stream>>>(head, tail, edge_type, kgCur, kgPay);
        scatter_user<<<PB, 512, 0, stream>>>(irows, icols, ivals, uCur, uPay);
        small_dense<<<1, 64, 0, stream>>>(latent_emb, weight, W_weight_att,
                                          b_weight_att, W1, b1, W2, b2,
                                          Pbuf, cbuf, lat_out);
        acc_kg<<<NBK, 1024, 0, stream>>>(kgPay, kgOffs, entity_emb, weight, ent_out);
        acc_user<<<NBU, 1024, 0, stream>>>(uPay, uOffs, entity_emb, user_emb,
                                           Pbuf, cbuf, W_user_att, b_user_att,
                                           lat_out, user_out);
    } else {
        // ---------- fallback atomic path ----------
        float* cnt   = (float*)d_ws;
        float* Pbuf2 = cnt + N_ENTITIES;
        float* cbuf2 = Pbuf2 + 64 * 8;
        hipMemsetAsync(ent_out, 0,
                       (size_t)(N_ENTITIES + N_USERS) * EMB * sizeof(float), stream);
        hipMemsetAsync(cnt, 0, N_ENTITIES * sizeof(float), stream);
        int blocks_edges = (N_EDGES * 64) / 256;
        kg_scatter<<<blocks_edges, 256, 0, stream>>>(head, tail, edge_type, entity_emb,
                                                     weight, ent_out, cnt);
        user_scatter<<<blocks_edges, 256, 0, stream>>>(irows, icols, ivals, entity_emb,
                                                       user_out);
        small_dense<<<1, 64, 0, stream>>>(latent_emb, weight, W_weight_att,
                                          b_weight_att, W1, b1, W2, b2,
                                          Pbuf2, cbuf2, lat_out);
        user_finalize<<<(N_USERS * 64) / 256, 256, 0, stream>>>(user_emb, Pbuf2, cbuf2,
                                                                W_user_att, b_user_att,
                                                                lat_out, user_out);
        entity_div<<<(N_ENTITIES * EMB) / 256, 256, 0, stream>>>(ent_out, cnt);
    }
}

// Round 6
// 448.544 us; speedup vs baseline: 4.6998x; 1.0460x over previous
//
#include <hip/hip_runtime.h>
#include <hip/hip_bf16.h>

#define N_USERS    50000
#define N_ENTITIES 100000
#define EMB        64
#define N_EDGES    2000000
#define NNZ        2000000
#define SLOPE      0.2f

// ---- bucket geometry -------------------------------------------------------
#define KROWS   256                 // entity rows per bucket
#define KSHIFT  8
#define NBK     391                 // ceil(100000/256)
#define UROWS   128                 // user rows per bucket
#define USHIFT  7
#define NBU     391                 // ceil(50000/128)
#define CAPK    8192                // LDS payload capacity (kg, 4 B)
#define CAPU    7680                // LDS payload capacity (user, 8 B)
#define CHUNK   8192                // edges per partition block
#define PB      ((N_EDGES + CHUNK - 1) / CHUNK)      // 245

// ============================================================================
// Pass 0: fused bucket histograms (LDS-privatized)
// ============================================================================
__global__ __launch_bounds__(512) void hist_both(const int* __restrict__ head,
                                                 const int* __restrict__ urows,
                                                 int* __restrict__ kgOffs,
                                                 int* __restrict__ uOffs) {
    __shared__ int lhk[NBK];
    __shared__ int lhu[NBU];
    int tid = threadIdx.x;
    for (int t = tid; t < NBK; t += 512) lhk[t] = 0;
    for (int t = tid; t < NBU; t += 512) lhu[t] = 0;
    __syncthreads();
    int base = blockIdx.x * CHUNK;
#pragma unroll 4
    for (int j = 0; j < CHUNK / 512; ++j) {
        int i = base + j * 512 + tid;
        if (i < N_EDGES) atomicAdd(&lhk[head[i] >> KSHIFT], 1);
        if (i < NNZ)     atomicAdd(&lhu[urows[i] >> USHIFT], 1);
    }
    __syncthreads();
    for (int t = tid; t < NBK; t += 512) { int c = lhk[t]; if (c) atomicAdd(&kgOffs[t], c); }
    for (int t = tid; t < NBU; t += 512) { int c = lhu[t]; if (c) atomicAdd(&uOffs[t], c); }
}

// ============================================================================
// Pass 1: exclusive scan of both bucket histograms (grid = 2 blocks)
// ============================================================================
__global__ __launch_bounds__(512) void scan_both(int* __restrict__ kgOffs,
                                                 int* __restrict__ kgCur,
                                                 int* __restrict__ uOffs,
                                                 int* __restrict__ uCur) {
    __shared__ int tsum[512];
    int n     = (blockIdx.x == 0) ? NBK : NBU;   // both 391
    int* offs = (blockIdx.x == 0) ? kgOffs : uOffs;
    int* cur  = (blockIdx.x == 0) ? kgCur  : uCur;
    int tid = threadIdx.x;
    int v = (tid < n) ? offs[tid] : 0;
    tsum[tid] = v;
    __syncthreads();
    for (int off = 1; off < 512; off <<= 1) {
        int t = (tid >= off) ? tsum[tid - off] : 0;
        __syncthreads();
        tsum[tid] += t;
        __syncthreads();
    }
    if (tid < n) { int e = tsum[tid] - v; offs[tid] = e; cur[tid] = e; }
    if (tid == n - 1) offs[n] = tsum[tid];
}

// ============================================================================
// Pass 2 (merged): bucket partition with block-local reservation.
// blocks [0,PB) handle kg edges; [PB,2*PB) handle user nnz.
// kg payload: tail(0..16) | type-1 (17..20) | rowlow (21..28)
// user payload: int2 { col(0..16) | rowlow(17..23), val_bits }
// ============================================================================
__global__ __launch_bounds__(512) void scatter_both(const int* __restrict__ head,
                                                    const int* __restrict__ tail,
                                                    const int* __restrict__ etype,
                                                    int* __restrict__ kgCur,
                                                    int* __restrict__ kgPay,
                                                    const int* __restrict__ urows,
                                                    const int* __restrict__ ucols,
                                                    const float* __restrict__ uvals,
                                                    int* __restrict__ uCur,
                                                    int2* __restrict__ uPay) {
    __shared__ int lh[NBK];      // NBK == NBU == 391
    __shared__ int lb[NBK];
    int tid = threadIdx.x;
    bool isKg = blockIdx.x < PB;
    int base = (isKg ? blockIdx.x : blockIdx.x - PB) * CHUNK;

    for (int t = tid; t < NBK; t += 512) lh[t] = 0;
    __syncthreads();
    if (isKg) {
#pragma unroll 4
        for (int j = 0; j < CHUNK / 512; ++j) {
            int i = base + j * 512 + tid;
            if (i < N_EDGES) atomicAdd(&lh[head[i] >> KSHIFT], 1);
        }
    } else {
#pragma unroll 4
        for (int j = 0; j < CHUNK / 512; ++j) {
            int i = base + j * 512 + tid;
            if (i < NNZ) atomicAdd(&lh[urows[i] >> USHIFT], 1);
        }
    }
    __syncthreads();
    int* cur = isKg ? kgCur : uCur;
    for (int t = tid; t < NBK; t += 512) {
        int c = lh[t];
        lb[t] = c ? atomicAdd(&cur[t], c) : 0;
        lh[t] = 0;
    }
    __syncthreads();
    if (isKg) {
#pragma unroll 4
        for (int j = 0; j < CHUNK / 512; ++j) {
            int i = base + j * 512 + tid;
            if (i < N_EDGES) {
                int h = head[i];
                int b = h >> KSHIFT;
                int p = lb[b] + atomicAdd(&lh[b], 1);
                kgPay[p] = tail[i] | ((etype[i] - 1) << 17) | ((h & (KROWS - 1)) << 21);
            }
        }
    } else {
#pragma unroll 4
        for (int j = 0; j < CHUNK / 512; ++j) {
            int i = base + j * 512 + tid;
            if (i < NNZ) {
                int r = urows[i];
                int b = r >> USHIFT;
                int p = lb[b] + atomicAdd(&lh[b], 1);
                uPay[p] = make_int2(ucols[i] | ((r & (UROWS - 1)) << 17),
                                    __float_as_int(uvals[i]));
            }
        }
    }
}

// ============================================================================
// Pass 3 (merged): accumulate. blocks [0,NBK) = kg buckets (in-LDS counting
// sort to exact row, per-wave register accumulation, mean fused); blocks
// [NBK,NBK+NBU) = user buckets (same + fused attention gating epilogue).
// Union'd LDS: kg needs 35.8 KB, user needs 63.0 KB -> 63 KB block.
// ============================================================================
__global__ __launch_bounds__(1024, 8) void acc_both(
        const int* __restrict__ kgPay, const int* __restrict__ kgOffs,
        const int2* __restrict__ uPay, const int* __restrict__ uOffs,
        const float* __restrict__ entity_emb,
        const float* __restrict__ weight,
        const float* __restrict__ user_emb,
        const float* __restrict__ P,
        const float* __restrict__ cvec,
        const float* __restrict__ W_user_att,
        const float* __restrict__ b_user_att,
        const float* __restrict__ latent_new,
        float* __restrict__ ent_out,
        float* __restrict__ user_out) {
    __shared__ long long smem8[7873];   // 62984 B union
    int t = threadIdx.x, d = t & 63, wv = t >> 6;    // wv 0..15

    if (blockIdx.x < NBK) {
        // ---------------- KG bucket ----------------
        int* spay = (int*)smem8;                 // CAPK ints
        int* lcnt = spay + CAPK;                 // 256
        int* lofs = lcnt + KROWS;                // 257
        int* sc   = lofs + KROWS + 1;            // 256
        int start = kgOffs[blockIdx.x], end = kgOffs[blockIdx.x + 1];
        int n = end - start; if (n > CAPK) n = CAPK;

        if (t < KROWS) lcnt[t] = 0;
        __syncthreads();
        for (int i = t; i < n; i += 1024)
            atomicAdd(&lcnt[(kgPay[start + i] >> 21) & (KROWS - 1)], 1);
        __syncthreads();
        if (t < KROWS) sc[t] = lcnt[t];
        __syncthreads();
        for (int off = 1; off < KROWS; off <<= 1) {
            int v = (t < KROWS && t >= off) ? sc[t - off] : 0;
            __syncthreads();
            if (t < KROWS) sc[t] += v;
            __syncthreads();
        }
        if (t < KROWS) { int e = sc[t] - lcnt[t]; lofs[t] = e; lcnt[t] = e; }
        if (t == 0) lofs[KROWS] = n;
        __syncthreads();
        for (int i = t; i < n; i += 1024) {
            int v = kgPay[start + i];
            int p = atomicAdd(&lcnt[(v >> 21) & (KROWS - 1)], 1);
            spay[p] = v;
        }
        __syncthreads();

        int rowbase = blockIdx.x * KROWS;
        for (int rr = 0; rr < KROWS / 16; ++rr) {
            int r = wv * (KROWS / 16) + rr;
            int gr = rowbase + r;
            if (gr >= N_ENTITIES) break;          // wave-uniform; last block only
            int s0 = lofs[r], e0 = lofs[r + 1];
            int cnt = e0 - s0;
            float acc = 0.f;
            int i = s0;
            for (; i + 7 < e0; i += 8) {
                float a0 = 0.f, a1 = 0.f;
#pragma unroll
                for (int u = 0; u < 8; u += 2) {
                    int va = spay[i + u], vb = spay[i + u + 1];
                    a0 += entity_emb[(va & 0x1FFFF) * EMB + d] * weight[((va >> 17) & 15) * EMB + d];
                    a1 += entity_emb[(vb & 0x1FFFF) * EMB + d] * weight[((vb >> 17) & 15) * EMB + d];
                }
                acc += a0 + a1;
            }
            for (; i < e0; ++i) {
                int v = spay[i];
                acc += entity_emb[(v & 0x1FFFF) * EMB + d] * weight[((v >> 17) & 15) * EMB + d];
            }
            // overflow tail (statistically never taken; cap = mean + ~36 sigma)
            for (int j = start + CAPK; j < end; ++j) {
                int v = kgPay[j];
                if (((v >> 21) & (KROWS - 1)) == r) {
                    acc += entity_emb[(v & 0x1FFFF) * EMB + d] * weight[((v >> 17) & 15) * EMB + d];
                    ++cnt;
                }
            }
            ent_out[gr * EMB + d] = acc / fmaxf((float)cnt, 1.f);
        }
    } else {
        // ---------------- USER bucket ----------------
        int2* spay = (int2*)smem8;               // CAPU int2
        int* lcnt = (int*)(spay + CAPU);         // 128
        int* lofs = lcnt + UROWS;                // 129
        int* sc   = lofs + UROWS + 1;            // 128
        int bk = blockIdx.x - NBK;
        int start = uOffs[bk], end = uOffs[bk + 1];
        int n = end - start; if (n > CAPU) n = CAPU;

        if (t < UROWS) lcnt[t] = 0;
        __syncthreads();
        for (int i = t; i < n; i += 1024)
            atomicAdd(&lcnt[(uPay[start + i].x >> 17) & (UROWS - 1)], 1);
        __syncthreads();
        if (t < UROWS) sc[t] = lcnt[t];
        __syncthreads();
        for (int off = 1; off < UROWS; off <<= 1) {
            int v = (t < UROWS && t >= off) ? sc[t - off] : 0;
            __syncthreads();
            if (t < UROWS) sc[t] += v;
            __syncthreads();
        }
        if (t < UROWS) { int e = sc[t] - lcnt[t]; lofs[t] = e; lcnt[t] = e; }
        if (t == 0) lofs[UROWS] = n;
        __syncthreads();
        for (int i = t; i < n; i += 1024) {
            int2 v = uPay[start + i];
            int p = atomicAdd(&lcnt[(v.x >> 17) & (UROWS - 1)], 1);
            spay[p] = v;
        }
        __syncthreads();

        int rowbase = bk * UROWS;
        for (int rr = 0; rr < UROWS / 16; ++rr) {
            int r = wv * (UROWS / 16) + rr;
            int gr = rowbase + r;
            if (gr >= N_USERS) break;             // wave-uniform; last block only
            int s0 = lofs[r], e0 = lofs[r + 1];
            float acc = 0.f;
            int i = s0;
            for (; i + 7 < e0; i += 8) {
                float a0 = 0.f, a1 = 0.f;
#pragma unroll
                for (int u = 0; u < 8; u += 2) {
                    int2 va = spay[i + u], vb = spay[i + u + 1];
                    a0 += __int_as_float(va.y) * entity_emb[(va.x & 0x1FFFF) * EMB + d];
                    a1 += __int_as_float(vb.y) * entity_emb[(vb.x & 0x1FFFF) * EMB + d];
                }
                acc += a0 + a1;
            }
            for (; i < e0; ++i) {
                int2 v = spay[i];
                acc += __int_as_float(v.y) * entity_emb[(v.x & 0x1FFFF) * EMB + d];
            }
            for (int j = start + CAPU; j < end; ++j) {   // overflow (never taken)
                int2 v = uPay[j];
                if (((v.x >> 17) & (UROWS - 1)) == r)
                    acc += __int_as_float(v.y) * entity_emb[(v.x & 0x1FFFF) * EMB + d];
            }

            // fused attention gating epilogue for this row
            float ue = user_emb[gr * EMB + d];
            float s[8];
#pragma unroll
            for (int f = 0; f < 8; ++f) s[f] = ue * P[d * 8 + f];
#pragma unroll
            for (int off = 32; off; off >>= 1) {
#pragma unroll
                for (int f = 0; f < 8; ++f) s[f] += __shfl_xor(s[f], off, 64);
            }
#pragma unroll
            for (int f = 0; f < 8; ++f) s[f] += cvec[f];
            float att[8];
            float mx = -1e30f;
#pragma unroll
            for (int k = 0; k < 8; ++k) {
                float a = b_user_att[k];
#pragma unroll
                for (int j = 0; j < 8; ++j) a += s[j] * W_user_att[k * 8 + j];
                a = a > 0.f ? a : SLOPE * a;
                att[k] = a;
                mx = fmaxf(mx, a);
            }
            float sum = 0.f;
#pragma unroll
            for (int k = 0; k < 8; ++k) { att[k] = __expf(att[k] - mx); sum += att[k]; }
            float inv = 1.f / sum;
            float g = 0.f;
#pragma unroll
            for (int f = 0; f < 8; ++f) g += att[f] * inv * latent_new[f * EMB + d];
            user_out[gr * EMB + d] = acc * (1.f + g);
        }
    }
}

// ============================================================================
// Small dense math (one wave): latent_new, P = W1^T·lat1^T, c = b1·lat1^T
// ============================================================================
__global__ void small_dense(const float* __restrict__ latent_emb,
                            const float* __restrict__ weight,
                            const float* __restrict__ W_weight_att,
                            const float* __restrict__ b_weight_att,
                            const float* __restrict__ W1,
                            const float* __restrict__ b1,
                            const float* __restrict__ W2,
                            const float* __restrict__ b2,
                            float* __restrict__ P_out,
                            float* __restrict__ c_out,
                            float* __restrict__ latent_new_out) {
    __shared__ float lat1[8 * 64];
    __shared__ float lat2[8 * 64];
    __shared__ float wl2[16 * 64];
    __shared__ float srp[8 * 16];
    __shared__ float soft[8 * 16];
    int l = threadIdx.x;  // 0..63

    for (int f = 0; f < 8; ++f) {
        float a1 = b1[l], a2 = b2[l];
        for (int k = 0; k < 64; ++k) {
            float le = latent_emb[f * 64 + k];
            a1 += le * W1[l * 64 + k];
            a2 += le * W2[l * 64 + k];
        }
        lat1[f * 64 + l] = a1;
        lat2[f * 64 + l] = a2;
    }
    for (int r = 0; r < 16; ++r) {
        float a = b2[l];
        for (int k = 0; k < 64; ++k) a += weight[r * 64 + k] * W2[l * 64 + k];
        wl2[r * 64 + l] = a;
    }
    __syncthreads();

    for (int f = 0; f < 8; ++f) {
        float p = 0.f;
        for (int d = 0; d < 64; ++d) p += W1[d * 64 + l] * lat1[f * 64 + d];
        P_out[l * 8 + f] = p;
    }
    if (l < 8) {
        float cc = 0.f;
        for (int d = 0; d < 64; ++d) cc += b1[d] * lat1[l * 64 + d];
        c_out[l] = cc;
    }
    for (int idx = l; idx < 128; idx += 64) {
        int f = idx >> 4, r = idx & 15;
        float a = 0.f;
        for (int d = 0; d < 64; ++d) a += lat2[f * 64 + d] * wl2[r * 64 + d];
        srp[idx] = a;
    }
    __syncthreads();

    if (l < 8) {
        int f = l;
        float att[16];
        float mx = -1e30f;
        for (int k = 0; k < 16; ++k) {
            float a = b_weight_att[k];
            for (int j = 0; j < 16; ++j) a += srp[f * 16 + j] * W_weight_att[k * 16 + j];
            a = a > 0.f ? a : SLOPE * a;
            att[k] = a;
            mx = fmaxf(mx, a);
        }
        float s = 0.f;
        for (int k = 0; k < 16; ++k) { att[k] = expf(att[k] - mx); s += att[k]; }
        float inv = 1.f / s;
        for (int k = 0; k < 16; ++k) soft[f * 16 + k] = att[k] * inv;
    }
    __syncthreads();

    for (int f = 0; f < 8; ++f) {
        float a = 0.f;
        for (int r = 0; r < 16; ++r) a += soft[f * 16 + r] * weight[r * 64 + l];
        latent_new_out[f * 64 + l] = a;
    }
}

// ============================================================================
// Fallback atomic path (verified) — only if ws too small
// ============================================================================
__global__ void kg_scatter(const int* __restrict__ head, const int* __restrict__ tail,
                           const int* __restrict__ etype,
                           const float* __restrict__ entity_emb,
                           const float* __restrict__ weight,
                           float* __restrict__ sums, float* __restrict__ cnt) {
    int gid = blockIdx.x * blockDim.x + threadIdx.x;
    int e = gid >> 6, d = threadIdx.x & 63;
    if (e >= N_EDGES) return;
    int h = head[e], t = tail[e], w = etype[e] - 1;
    float v = entity_emb[t * EMB + d] * weight[w * EMB + d];
    unsafeAtomicAdd(&sums[h * EMB + d], v);
    if (d == 0) unsafeAtomicAdd(&cnt[h], 1.0f);
}

__global__ void user_scatter(const int* __restrict__ rows, const int* __restrict__ cols,
                             const float* __restrict__ vals,
                             const float* __restrict__ entity_emb,
                             float* __restrict__ user_sums) {
    int gid = blockIdx.x * blockDim.x + threadIdx.x;
    int e = gid >> 6, d = threadIdx.x & 63;
    if (e >= NNZ) return;
    float v = vals[e] * entity_emb[cols[e] * EMB + d];
    unsafeAtomicAdd(&user_sums[rows[e] * EMB + d], v);
}

__global__ void entity_div(float* __restrict__ ent, const float* __restrict__ cnt) {
    int gid = blockIdx.x * blockDim.x + threadIdx.x;
    if (gid >= N_ENTITIES * EMB) return;
    float c = cnt[gid >> 6];
    ent[gid] = ent[gid] / fmaxf(c, 1.0f);
}

__global__ void user_finalize(const float* __restrict__ user_emb,
                              const float* __restrict__ P,
                              const float* __restrict__ c,
                              const float* __restrict__ W_user_att,
                              const float* __restrict__ b_user_att,
                              const float* __restrict__ latent_new,
                              float* __restrict__ user_out) {
    int gid = blockIdx.x * blockDim.x + threadIdx.x;
    int u = gid >> 6, lane = threadIdx.x & 63;
    if (u >= N_USERS) return;
    float ue = user_emb[u * 64 + lane];
    float s[8];
#pragma unroll
    for (int f = 0; f < 8; ++f) s[f] = ue * P[lane * 8 + f];
#pragma unroll
    for (int off = 32; off; off >>= 1)
#pragma unroll
        for (int f = 0; f < 8; ++f) s[f] += __shfl_xor(s[f], off, 64);
#pragma unroll
    for (int f = 0; f < 8; ++f) s[f] += c[f];
    float att[8], mx = -1e30f;
#pragma unroll
    for (int k = 0; k < 8; ++k) {
        float a = b_user_att[k];
#pragma unroll
        for (int j = 0; j < 8; ++j) a += s[j] * W_user_att[k * 8 + j];
        a = a > 0.f ? a : SLOPE * a;
        att[k] = a;
        mx = fmaxf(mx, a);
    }
    float sum = 0.f;
#pragma unroll
    for (int k = 0; k < 8; ++k) { att[k] = expf(att[k] - mx); sum += att[k]; }
    float inv = 1.f / sum, g = 0.f;
#pragma unroll
    for (int f = 0; f < 8; ++f) g += att[f] * inv * latent_new[f * 64 + lane];
    float ua = user_out[u * 64 + lane];
    user_out[u * 64 + lane] = ua * (1.f + g);
}

extern "C" void kernel_launch(void* const* d_in, const int* in_sizes, int n_in,
                              void* d_out, int out_size, void* d_ws, size_t ws_size,
                              hipStream_t stream) {
    const float* entity_emb   = (const float*)d_in[0];
    const float* user_emb     = (const float*)d_in[1];
    const float* latent_emb   = (const float*)d_in[2];
    const int*   edge_index   = (const int*)d_in[3];
    const int*   edge_type    = (const int*)d_in[4];
    const int*   irows        = (const int*)d_in[5];
    const int*   icols        = (const int*)d_in[6];
    const float* ivals        = (const float*)d_in[7];
    const float* weight       = (const float*)d_in[8];
    const float* W_user_att   = (const float*)d_in[10];
    const float* b_user_att   = (const float*)d_in[11];
    const float* W_weight_att = (const float*)d_in[12];
    const float* b_weight_att = (const float*)d_in[13];
    const float* W1           = (const float*)d_in[14];
    const float* b1           = (const float*)d_in[15];
    const float* W2           = (const float*)d_in[16];
    const float* b2           = (const float*)d_in[17];

    float* out      = (float*)d_out;
    float* ent_out  = out;
    float* user_out = out + (size_t)N_ENTITIES * EMB;
    float* lat_out  = user_out + (size_t)N_USERS * EMB;

    const int* head = edge_index;
    const int* tail = edge_index + N_EDGES;

    // ---- workspace layout ----
    int* ws_i = (int*)d_ws;
    int*   kgOffs = ws_i;                       // NBK+1 = 392
    int*   uOffs  = kgOffs + (NBK + 1);         // NBU+1 = 392
    int*   kgCur  = uOffs + (NBU + 1);          // 391
    int*   uCur   = kgCur + NBK;                // 391
    int*   kgPay  = uCur + NBU;                 // 2,000,000 int
    int2*  uPay   = (int2*)(kgPay + N_EDGES);   // 2,000,000 int2 (8 B aligned)
    float* Pbuf   = (float*)(uPay + NNZ);       // 512
    float* cbuf   = Pbuf + 64 * 8;              // 8
    size_t need_bytes = (size_t)((NBK + 1) + (NBU + 1) + NBK + NBU +
                                 N_EDGES + 2 * (size_t)NNZ + 512 + 8) * 4;

    if (ws_size >= need_bytes) {
        // zero both histogram regions in one memset (contiguous)
        hipMemsetAsync(kgOffs, 0, (size_t)((NBK + 1) + (NBU + 1)) * sizeof(int), stream);

        hist_both<<<PB, 512, 0, stream>>>(head, irows, kgOffs, uOffs);
        scan_both<<<2, 512, 0, stream>>>(kgOffs, kgCur, uOffs, uCur);
        scatter_both<<<2 * PB, 512, 0, stream>>>(head, tail, edge_type, kgCur, kgPay,
                                                 irows, icols, ivals, uCur, uPay);
        small_dense<<<1, 64, 0, stream>>>(latent_emb, weight, W_weight_att,
                                          b_weight_att, W1, b1, W2, b2,
                                          Pbuf, cbuf, lat_out);
        acc_both<<<NBK + NBU, 1024, 0, stream>>>(kgPay, kgOffs, uPay, uOffs,
                                                 entity_emb, weight, user_emb,
                                                 Pbuf, cbuf, W_user_att, b_user_att,
                                                 lat_out, ent_out, user_out);
    } else {
        // ---------- fallback atomic path ----------
        float* cnt   = (float*)d_ws;
        float* Pbuf2 = cnt + N_ENTITIES;
        float* cbuf2 = Pbuf2 + 64 * 8;
        hipMemsetAsync(ent_out, 0,
                       (size_t)(N_ENTITIES + N_USERS) * EMB * sizeof(float), stream);
        hipMemsetAsync(cnt, 0, N_ENTITIES * sizeof(float), stream);
        int blocks_edges = (N_EDGES * 64) / 256;
        kg_scatter<<<blocks_edges, 256, 0, stream>>>(head, tail, edge_type, entity_emb,
                                                     weight, ent_out, cnt);
        user_scatter<<<blocks_edges, 256, 0, stream>>>(irows, icols, ivals, entity_emb,
                                                       user_out);
        small_dense<<<1, 64, 0, stream>>>(latent_emb, weight, W_weight_att,
                                          b_weight_att, W1, b1, W2, b2,
                                          Pbuf2, cbuf2, lat_out);
        user_finalize<<<(N_USERS * 64) / 256, 256, 0, stream>>>(user_emb, Pbuf2, cbuf2,
                                                                W_user_att, b_user_att,
                                                                lat_out, user_out);
        entity_div<<<(N_ENTITIES * EMB) / 256, 256, 0, stream>>>(ent_out, cnt);
    }
}